// Round 2
// baseline (177.441 us; speedup 1.0000x reference)
//
#include <hip/hip_runtime.h>

// MTFNet: N=8, C=8, H=W=256, L=11, SF=2, h=w=128
// Pipeline (v4):
//  K1: blur_fused — stages 25-row x window in LDS (reflect halo), computes
//      E2[n][c'][p] = blur(x,k)-y transposed-flat, AND writes xpad rows
//      (16 rows/block, exact cover) so the separate pad kernel is gone.
//      XCD-contiguous block swizzle: each XCD owns 8 consecutive nc slices.
//  K2: grad — G[n][ki*11+kj][c] contraction, reads xpad from same-XCD L2
//      (same bijective swizzle as K1: nc -> XCD nc/8).
//  K3: pronet v3 (unchanged): 352 active threads, b128 weight loads.
// Fallback (ws too small for xpad): R3's scalar-load blur/grad (known-good).
// NOTE: dur_us includes ~100 us of harness reset (268MB ws poison + input
// restore) — fills show as ~45us dispatches in rocprof.

__device__ __forceinline__ int refl(int m) {
    m = (m < 0) ? -m : m;
    return (m > 255) ? (510 - m) : m;
}

#define XPROW 272   // 256 + 8 halo each side

// ---------------- K1: fused pad+blur ----------------
// Block = (nc, rowblk). Stages rows [16*rowblk-5, 16*rowblk+19] of x into
// LDS with reflect (row + column halo), writes xpad rows [16*rowblk,+15],
// computes blur rows [8*rowblk, 8*rowblk+7] from LDS, stores E2 transposed.
__global__ __launch_bounds__(256) void blur_fused_kernel(
        const float* __restrict__ x, const float* __restrict__ y,
        const float* __restrict__ kk, float* __restrict__ E2,
        float* __restrict__ xp) {
    __shared__ float kl[121];
    __shared__ __align__(16) float S[25][XPROW];   // 27.2 KB
    int bid = blockIdx.x;
    // bijective XCD swizzle: 1024 blocks, XCD x gets orig in [128x, 128x+128)
    // -> nc in [8x, 8x+8): all 16 rowblks of one nc land on one XCD.
    int orig = ((bid & 7) << 7) | (bid >> 3);
    int rowblk = orig & 15;
    int nc = orig >> 4;
    int t = threadIdx.x;
    const float* xb = x + nc * 65536;
    if (t < 121) kl[t] = kk[nc * 121 + t];

    int rowbase = 16 * rowblk - 5;
    // stage 25 rows x 64 float4 (core columns, shifted +8 for halo)
    for (int i = t; i < 1600; i += 256) {
        int s = i >> 6, c4 = i & 63;
        int src = refl(rowbase + s);
        float4 v = reinterpret_cast<const float4*>(xb + src * 256)[c4];
        *reinterpret_cast<float4*>(&S[s][8 + 4 * c4]) = v;
    }
    // column halos: 25 rows x 8 each side (reflect without edge repeat)
    if (t < 200) {
        int s = t >> 3, u = t & 7;
        const float* srow = xb + refl(rowbase + s) * 256;
        S[s][7 - u]   = srow[1 + u];
        S[s][264 + u] = srow[254 - u];
    }
    __syncthreads();

    // side-product: write xpad rows 16*rowblk..+15 (LDS rows s=5..20).
    // fire-and-forget stores; issue early so they drain under compute.
    float* xpb = xp + nc * (256 * XPROW);
    for (int i = t; i < 1088; i += 256) {
        int rr = i / 68, c4 = i - rr * 68;
        *reinterpret_cast<float4*>(&xpb[(16 * rowblk + rr) * XPROW + 4 * c4]) =
            *reinterpret_cast<const float4*>(&S[rr + 5][4 * c4]);
    }

    // blur compute from LDS
    int ty = t >> 5;
    int r = rowblk * 8 + ty;
    int ps0 = (t & 31) * 4;
    float a0 = 0.f, a1 = 0.f, a2 = 0.f, a3 = 0.f;
    #pragma unroll
    for (int i = 0; i < 11; ++i) {
        // raw row 2r-5+i  ->  LDS row (2r-5+i) - (16*rowblk-5) = 2*ty+i
        const float4* row4 = reinterpret_cast<const float4*>(&S[2 * ty + i][2 * ps0]);
        float w[24];
        #pragma unroll
        for (int q = 0; q < 6; ++q) {
            float4 v = row4[q];
            w[4 * q] = v.x; w[4 * q + 1] = v.y; w[4 * q + 2] = v.z; w[4 * q + 3] = v.w;
        }
        #pragma unroll
        for (int j = 0; j < 11; ++j) {
            float kv = kl[i * 11 + j];
            a0 = fmaf(w[j + 3], kv, a0);
            a1 = fmaf(w[j + 5], kv, a1);
            a2 = fmaf(w[j + 7], kv, a2);
            a3 = fmaf(w[j + 9], kv, a3);
        }
    }
    int n = nc >> 3;
    int o = nc * 16384 + r * 128 + ps0;
    float4 yv = *reinterpret_cast<const float4*>(y + o);
    float e[4] = {a0 - yv.x, a1 - yv.y, a2 - yv.z, a3 - yv.w};
    int qn = o - n * 131072;
    int p = qn >> 3;
    int cbase = qn & 7;
    float* eb = E2 + n * 131072 + p;
    #pragma unroll
    for (int qq = 0; qq < 4; ++qq)
        eb[(cbase + qq) * 16384] = e[qq];
}

// ---------------- K2: G contraction (padded loads, XCD swizzle) ----------
__global__ __launch_bounds__(256) void grad_kernel(
        const float* __restrict__ xp, const float* __restrict__ E2,
        float* __restrict__ G) {
    int bid = blockIdx.x;
    // bijective XCD swizzle: 704 blocks, XCD x gets orig in [88x, 88x+88)
    // -> nc in [8x, 8x+8): same XCD that produced this nc's xpad in K1.
    int orig = (bid & 7) * 88 + (bid >> 3);
    int ki = orig % 11;
    int nc = orig / 11;
    int n = nc >> 3, c = nc & 7;
    const float* xb = xp + nc * (256 * XPROW);
    const float* Eb = E2 + n * 131072 + c * 16384;
    int t = threadIdx.x;
    int ps0 = (t & 31) * 4;
    int pr0 = t >> 5;
    float acc[11];
    #pragma unroll
    for (int j = 0; j < 11; ++j) acc[j] = 0.f;
    for (int it = 0; it < 16; ++it) {
        int pr = pr0 + (it << 3);
        int iy = refl(ki + 2 * pr - 5);
        float4 ev = *reinterpret_cast<const float4*>(Eb + pr * 128 + ps0);
        const float4* row4 = reinterpret_cast<const float4*>(xb + iy * XPROW + 2 * ps0);
        float w[24];
        #pragma unroll
        for (int q = 0; q < 6; ++q) {
            float4 v = row4[q];
            w[4 * q] = v.x; w[4 * q + 1] = v.y; w[4 * q + 2] = v.z; w[4 * q + 3] = v.w;
        }
        #pragma unroll
        for (int j = 0; j < 11; ++j) {
            float v = acc[j];
            v = fmaf(w[j + 3], ev.x, v);
            v = fmaf(w[j + 5], ev.y, v);
            v = fmaf(w[j + 7], ev.z, v);
            v = fmaf(w[j + 9], ev.w, v);
            acc[j] = v;
        }
    }
    __shared__ float part[4][11];
    int lane = t & 63, wid = t >> 6;
    #pragma unroll
    for (int j = 0; j < 11; ++j) {
        float v = acc[j];
        #pragma unroll
        for (int off = 32; off > 0; off >>= 1)
            v += __shfl_down(v, off, 64);
        if (lane == 0) part[wid][j] = v;
    }
    __syncthreads();
    if (t < 11) {
        float s = part[0][t] + part[1][t] + part[2][t] + part[3][t];
        G[n * 968 + (ki * 11 + t) * 8 + c] = s * (1.0f / 16384.0f);
    }
}

// ---------------- Fallback kernels (R3, scalar loads, known-good) ----------
__global__ __launch_bounds__(256) void blur_kernel_ref(
        const float* __restrict__ x, const float* __restrict__ y,
        const float* __restrict__ kk, float* __restrict__ E2) {
    __shared__ float kl[121];
    int bid = blockIdx.x;
    int rowblk = bid & 15;
    int nc = bid >> 4;
    int t = threadIdx.x;
    if (t < 121) kl[t] = kk[nc * 121 + t];
    __syncthreads();
    int r = rowblk * 8 + (t >> 5);
    int ps0 = (t & 31) * 4;
    const float* xb = x + nc * 65536;
    float a0 = 0.f, a1 = 0.f, a2 = 0.f, a3 = 0.f;
    int cb = 2 * ps0 - 5;
    #pragma unroll
    for (int i = 0; i < 11; ++i) {
        int iy = refl(2 * r - 5 + i);
        const float* row = xb + iy * 256;
        float c[17];
        #pragma unroll
        for (int u = 0; u < 17; ++u) c[u] = row[refl(cb + u)];
        #pragma unroll
        for (int j = 0; j < 11; ++j) {
            float kv = kl[i * 11 + j];
            a0 = fmaf(c[j], kv, a0);
            a1 = fmaf(c[j + 2], kv, a1);
            a2 = fmaf(c[j + 4], kv, a2);
            a3 = fmaf(c[j + 6], kv, a3);
        }
    }
    int n = nc >> 3;
    int o = nc * 16384 + r * 128 + ps0;
    float4 yv = *reinterpret_cast<const float4*>(y + o);
    float e[4] = {a0 - yv.x, a1 - yv.y, a2 - yv.z, a3 - yv.w};
    int qn = o - n * 131072;
    int p = qn >> 3;
    int cbase = qn & 7;
    float* eb = E2 + n * 131072 + p;
    #pragma unroll
    for (int qq = 0; qq < 4; ++qq)
        eb[(cbase + qq) * 16384] = e[qq];
}

__global__ __launch_bounds__(256) void grad_kernel_ref(
        const float* __restrict__ x, const float* __restrict__ E2,
        float* __restrict__ G) {
    int bid = blockIdx.x;
    int ki = bid % 11;
    int nc = bid / 11;
    int n = nc >> 3, c = nc & 7;
    const float* xb = x + nc * 65536;
    const float* Eb = E2 + n * 131072 + c * 16384;
    int t = threadIdx.x;
    int ps0 = (t & 31) * 4;
    int pr0 = t >> 5;
    int cb = 2 * ps0 - 5;
    float acc[11];
    #pragma unroll
    for (int j = 0; j < 11; ++j) acc[j] = 0.f;
    for (int it = 0; it < 16; ++it) {
        int pr = pr0 + (it << 3);
        int iy = refl(ki + 2 * pr - 5);
        const float* row = xb + iy * 256;
        float cbuf[17];
        #pragma unroll
        for (int u = 0; u < 17; ++u) cbuf[u] = row[refl(cb + u)];
        float4 ev = *reinterpret_cast<const float4*>(Eb + pr * 128 + ps0);
        #pragma unroll
        for (int j = 0; j < 11; ++j) {
            float v = acc[j];
            v = fmaf(cbuf[j], ev.x, v);
            v = fmaf(cbuf[j + 2], ev.y, v);
            v = fmaf(cbuf[j + 4], ev.z, v);
            v = fmaf(cbuf[j + 6], ev.w, v);
            acc[j] = v;
        }
    }
    __shared__ float part[4][11];
    int lane = t & 63, wid = t >> 6;
    #pragma unroll
    for (int j = 0; j < 11; ++j) {
        float v = acc[j];
        #pragma unroll
        for (int off = 32; off > 0; off >>= 1)
            v += __shfl_down(v, off, 64);
        if (lane == 0) part[wid][j] = v;
    }
    __syncthreads();
    if (t < 11) {
        float s = part[0][t] + part[1][t] + part[2][t] + part[3][t];
        G[n * 968 + (ki * 11 + t) * 8 + c] = s * (1.0f / 16384.0f);
    }
}

// ---------------- K3: pronet v3 ----------------
// 384 threads (352 active = quarter 0..3 x co 0..7 x yy 0..10), 2 ci per thread.
// Weights padded to 12 floats/(co,ci) in LDS -> 3 x ds_read_b128 per ci.
// Partial sums exchanged via red[3][88][12] with float4 writes/reads.
struct PArgs {
    const float* W[9];
    const float* B[9];
    const float* k;
    const float* gamma;
    const float* G;
    float* out;
};

#define PLSTRIDE 20
#define WSTRIDE 12

__global__ __launch_bounds__(384) void pronet_kernel(PArgs pa) {
    __shared__ __align__(16) float P0[8 * 13 * PLSTRIDE];
    __shared__ __align__(16) float P1[8 * 13 * PLSTRIDE];
    __shared__ float G2[968];
    __shared__ float F[968];
    __shared__ __align__(16) float red[3 * 88 * WSTRIDE];
    __shared__ __align__(16) float wts[9 * 64 * WSTRIDE];
    __shared__ float bs[9 * 8];
    __shared__ float rowsum[88];
    __shared__ float inv[8];

    int n = blockIdx.x;
    int t = threadIdx.x;

    // stage weights padded: wts[(widx*64 + co*8+ci)*12 + q] = W[widx][(co*8+ci)*9 + q]
    #pragma unroll
    for (int widx = 0; widx < 9; ++widx) {
        const float* wsrc = pa.W[widx];
        for (int i = t; i < 576; i += 384) {
            int oc = i / 9, q = i - oc * 9;
            wts[(widx * 64 + oc) * WSTRIDE + q] = wsrc[i];
        }
        if (t < 8) bs[widx * 8 + t] = pa.B[widx][t];
    }
    for (int i = t; i < 8 * 13 * PLSTRIDE; i += 384) { P0[i] = 0.f; P1[i] = 0.f; }
    __syncthreads();

    float gm = pa.gamma[0] * 0.1f;
    for (int o = t; o < 968; o += 384) {
        float v = pa.k[n * 968 + o] - gm * pa.G[n * 968 + o];
        G2[o] = v;
        int co = o / 121, rem = o - co * 121;
        int yy = rem / 11, xx = rem - yy * 11;
        P0[(co * 13 + yy + 1) * PLSTRIDE + xx + 1] = v;
    }

    bool active = t < 352;
    int quarter = t / 88;            // 0..3 -> ci {2q, 2q+1}
    int id = t - quarter * 88;       // 0..87
    int co = id / 11, yy = id - co * 11;
    int ci0 = quarter * 2;

    // mode 0: P1 = relu(conv);  mode 1: P0 = relu(P0 + 0.1*conv);
    // mode 2: F  = relu(G2 + 0.1*conv)
    auto do_conv = [&](const float* Pin, int widx, int mode) {
        __syncthreads();
        float acc[12];
        if (active) {
            #pragma unroll
            for (int xx = 0; xx < 12; ++xx) acc[xx] = 0.f;
            #pragma unroll
            for (int cq = 0; cq < 2; ++cq) {
                int ci = ci0 + cq;
                const float4* wp4 = reinterpret_cast<const float4*>(
                    &wts[(widx * 64 + co * 8 + ci) * WSTRIDE]);
                float4 w0 = wp4[0], w1 = wp4[1], w2 = wp4[2];
                float wv[9] = {w0.x, w0.y, w0.z, w0.w, w1.x, w1.y, w1.z, w1.w, w2.x};
                float r[3][13];
                #pragma unroll
                for (int dy = 0; dy < 3; ++dy) {
                    const float* row = Pin + (ci * 13 + yy + dy) * PLSTRIDE;
                    float4 a = *reinterpret_cast<const float4*>(row);
                    float4 b = *reinterpret_cast<const float4*>(row + 4);
                    float4 c = *reinterpret_cast<const float4*>(row + 8);
                    r[dy][0] = a.x;  r[dy][1] = a.y;  r[dy][2]  = a.z;  r[dy][3]  = a.w;
                    r[dy][4] = b.x;  r[dy][5] = b.y;  r[dy][6]  = b.z;  r[dy][7]  = b.w;
                    r[dy][8] = c.x;  r[dy][9] = c.y;  r[dy][10] = c.z;  r[dy][11] = c.w;
                    r[dy][12] = row[12];
                }
                #pragma unroll
                for (int xx = 0; xx < 11; ++xx) {
                    float v = acc[xx];
                    v = fmaf(r[0][xx],     wv[0], v);
                    v = fmaf(r[0][xx + 1], wv[1], v);
                    v = fmaf(r[0][xx + 2], wv[2], v);
                    v = fmaf(r[1][xx],     wv[3], v);
                    v = fmaf(r[1][xx + 1], wv[4], v);
                    v = fmaf(r[1][xx + 2], wv[5], v);
                    v = fmaf(r[2][xx],     wv[6], v);
                    v = fmaf(r[2][xx + 1], wv[7], v);
                    v = fmaf(r[2][xx + 2], wv[8], v);
                    acc[xx] = v;
                }
            }
            if (quarter != 0) {
                float4* rp = reinterpret_cast<float4*>(
                    &red[((quarter - 1) * 88 + id) * WSTRIDE]);
                rp[0] = make_float4(acc[0], acc[1], acc[2],  acc[3]);
                rp[1] = make_float4(acc[4], acc[5], acc[6],  acc[7]);
                rp[2] = make_float4(acc[8], acc[9], acc[10], acc[11]);
            }
        }
        __syncthreads();
        if (active && quarter == 0) {
            float b = bs[widx * 8 + co];
            float oth[12];
            #pragma unroll
            for (int pq = 0; pq < 3; ++pq) {
                const float4* rp = reinterpret_cast<const float4*>(
                    &red[(pq * 88 + id) * WSTRIDE]);
                float4 v0 = rp[0], v1 = rp[1], v2 = rp[2];
                if (pq == 0) {
                    oth[0] = v0.x; oth[1] = v0.y; oth[2]  = v0.z; oth[3]  = v0.w;
                    oth[4] = v1.x; oth[5] = v1.y; oth[6]  = v1.z; oth[7]  = v1.w;
                    oth[8] = v2.x; oth[9] = v2.y; oth[10] = v2.z; oth[11] = v2.w;
                } else {
                    oth[0] += v0.x; oth[1] += v0.y; oth[2]  += v0.z; oth[3]  += v0.w;
                    oth[4] += v1.x; oth[5] += v1.y; oth[6]  += v1.z; oth[7]  += v1.w;
                    oth[8] += v2.x; oth[9] += v2.y; oth[10] += v2.z; oth[11] += v2.w;
                }
            }
            #pragma unroll
            for (int xx = 0; xx < 11; ++xx) {
                float v = acc[xx] + oth[xx] + b;
                int pidx = (co * 13 + yy + 1) * PLSTRIDE + xx + 1;
                if (mode == 0) {
                    P1[pidx] = fmaxf(v, 0.f);
                } else if (mode == 1) {
                    float p = P0[pidx];
                    P0[pidx] = fmaxf(fmaf(0.1f, v, p), 0.f);
                } else {
                    int fo = co * 121 + yy * 11 + xx;
                    F[fo] = fmaxf(fmaf(0.1f, v, G2[fo]), 0.f);
                }
            }
        }
    };

    #pragma unroll
    for (int rb = 0; rb < 4; ++rb) {
        do_conv(P0, 2 * rb, 0);
        do_conv(P1, 2 * rb + 1, 1);
    }
    do_conv(P0, 8, 2);
    __syncthreads();

    if (t < 88) {
        int tco = t / 11, tyy = t - tco * 11;
        float s = 0.f;
        #pragma unroll
        for (int xx = 0; xx < 11; ++xx) s += F[tco * 121 + tyy * 11 + xx];
        rowsum[t] = s;
    }
    __syncthreads();
    if (t < 8) {
        float s = 0.f;
        #pragma unroll
        for (int j = 0; j < 11; ++j) s += rowsum[t * 11 + j];
        inv[t] = 1.f / s;
    }
    __syncthreads();
    for (int o = t; o < 968; o += 384)
        pa.out[n * 968 + o] = F[o] * inv[o / 121];
}

extern "C" void kernel_launch(void* const* d_in, const int* in_sizes, int n_in,
                              void* d_out, int out_size, void* d_ws, size_t ws_size,
                              hipStream_t stream) {
    const float* x = (const float*)d_in[0];
    const float* y = (const float*)d_in[1];
    const float* k = (const float*)d_in[2];
    const float* gamma = (const float*)d_in[4];

    const size_t xpad_fl = (size_t)64 * 256 * XPROW;
    const size_t e2_fl = (size_t)8 * 131072;
    const size_t need = (xpad_fl + e2_fl + 7744) * sizeof(float);

    float* G;
    if (ws_size >= need) {
        float* xpad = (float*)d_ws;
        float* E2 = xpad + xpad_fl;
        G = E2 + e2_fl;
        blur_fused_kernel<<<1024, 256, 0, stream>>>(x, y, k, E2, xpad);
        grad_kernel<<<704, 256, 0, stream>>>(xpad, E2, G);
    } else {
        float* E2 = (float*)d_ws;
        G = E2 + e2_fl;
        blur_kernel_ref<<<1024, 256, 0, stream>>>(x, y, k, E2);
        grad_kernel_ref<<<704, 256, 0, stream>>>(x, E2, G);
    }

    PArgs pa;
    for (int i = 0; i < 9; ++i) {
        pa.W[i] = (const float*)d_in[5 + 2 * i];
        pa.B[i] = (const float*)d_in[6 + 2 * i];
    }
    pa.k = k;
    pa.gamma = gamma;
    pa.G = G;
    pa.out = (float*)d_out;
    pronet_kernel<<<8, 384, 0, stream>>>(pa);
}

// Round 3
// 168.132 us; speedup vs baseline: 1.0554x; 1.0554x over previous
//
#include <hip/hip_runtime.h>

// MTFNet: N=8, C=8, H=W=256, L=11, SF=2, h=w=128
// Pipeline (v5):
//  K0: pad — xpad[nc][256][272] column-reflect-padded x (halo 8), XCD swizzle.
//  K1: blur — E2[n][c'][p] = blur(x,k)-y transposed-flat, reads xpad (global,
//      vectorized, no LDS staging — LDS variant had 8-way bank conflicts).
//  K2: grad — G[n][ki*11+kj][c] contraction, same-XCD as its nc's K0/K1 blocks.
//  K3: pronet v4 — 704 threads (8 ci-groups x 88), 1 ci/thread, float4 weight
//      staging. 11 waves on the CU for latency hiding (was 6).
// Fallback (ws too small for xpad): R3's scalar-load blur/grad (known-good).
// NOTE: dur_us includes ~100 us of harness reset (268MB ws poison + input
// restore) — fills show as ~45us dispatches in rocprof.

__device__ __forceinline__ int refl(int m) {
    m = (m < 0) ? -m : m;
    return (m > 255) ? (510 - m) : m;
}

#define XPROW 272   // 256 + 8 halo each side

// ---------------- K0: column-pad x with reflection ----------------
__global__ __launch_bounds__(256) void pad_kernel(
        const float* __restrict__ x, float* __restrict__ xp) {
    int bid = blockIdx.x;
    // bijective XCD swizzle: 256 blocks -> XCD x owns orig [32x,32x+32)
    // -> nc in [8x,8x+8), matching K1/K2 nc grouping.
    int orig = (bid & 7) * 32 + (bid >> 3);
    int chunk = orig & 3;
    int nc = orig >> 2;
    int team = threadIdx.x >> 6;
    int lane = threadIdx.x & 63;
    const float* xb = x + nc * 65536;
    float* xpb = xp + nc * (256 * XPROW);
    for (int it = 0; it < 16; ++it) {
        int row = chunk * 64 + it * 4 + team;
        const float* src = xb + row * 256;
        float* dst = xpb + row * XPROW + 8;
        float4 v = reinterpret_cast<const float4*>(src)[lane];
        reinterpret_cast<float4*>(dst)[lane] = v;
        if (lane < 8) {
            dst[-1 - lane] = src[1 + lane];
        } else if (lane < 16) {
            int j = lane - 8;
            dst[256 + j] = src[254 - j];
        }
    }
}

// ---------------- K1: blur + subtract y, store transposed E2 --------------
__global__ __launch_bounds__(256) void blur_kernel(
        const float* __restrict__ xp, const float* __restrict__ y,
        const float* __restrict__ kk, float* __restrict__ E2) {
    __shared__ float kl[121];
    int bid = blockIdx.x;
    // bijective XCD swizzle: 1024 blocks -> XCD x owns orig [128x,128x+128)
    // -> nc in [8x,8x+8): all 16 rowblks of one nc on one XCD.
    int orig = ((bid & 7) << 7) | (bid >> 3);
    int rowblk = orig & 15;
    int nc = orig >> 4;
    int t = threadIdx.x;
    if (t < 121) kl[t] = kk[nc * 121 + t];
    __syncthreads();
    int r = rowblk * 8 + (t >> 5);
    int ps0 = (t & 31) * 4;
    const float* xb = xp + nc * (256 * XPROW);
    float a0 = 0.f, a1 = 0.f, a2 = 0.f, a3 = 0.f;
    #pragma unroll
    for (int i = 0; i < 11; ++i) {
        int iy = refl(2 * r - 5 + i);
        const float4* row4 = reinterpret_cast<const float4*>(xb + iy * XPROW + 2 * ps0);
        float w[24];
        #pragma unroll
        for (int q = 0; q < 6; ++q) {
            float4 v = row4[q];
            w[4 * q] = v.x; w[4 * q + 1] = v.y; w[4 * q + 2] = v.z; w[4 * q + 3] = v.w;
        }
        #pragma unroll
        for (int j = 0; j < 11; ++j) {
            float kv = kl[i * 11 + j];
            a0 = fmaf(w[j + 3], kv, a0);
            a1 = fmaf(w[j + 5], kv, a1);
            a2 = fmaf(w[j + 7], kv, a2);
            a3 = fmaf(w[j + 9], kv, a3);
        }
    }
    int n = nc >> 3;
    int o = nc * 16384 + r * 128 + ps0;
    float4 yv = *reinterpret_cast<const float4*>(y + o);
    float e[4] = {a0 - yv.x, a1 - yv.y, a2 - yv.z, a3 - yv.w};
    int qn = o - n * 131072;
    int p = qn >> 3;
    int cbase = qn & 7;
    float* eb = E2 + n * 131072 + p;
    #pragma unroll
    for (int qq = 0; qq < 4; ++qq)
        eb[(cbase + qq) * 16384] = e[qq];
}

// ---------------- K2: G contraction (padded loads, XCD swizzle) ----------
__global__ __launch_bounds__(256) void grad_kernel(
        const float* __restrict__ xp, const float* __restrict__ E2,
        float* __restrict__ G) {
    int bid = blockIdx.x;
    // bijective XCD swizzle: 704 blocks -> XCD x owns orig [88x,88x+88)
    // -> nc in [8x,8x+8): same XCD that produced this nc's xpad/E2.
    int orig = (bid & 7) * 88 + (bid >> 3);
    int ki = orig % 11;
    int nc = orig / 11;
    int n = nc >> 3, c = nc & 7;
    const float* xb = xp + nc * (256 * XPROW);
    const float* Eb = E2 + n * 131072 + c * 16384;
    int t = threadIdx.x;
    int ps0 = (t & 31) * 4;
    int pr0 = t >> 5;
    float acc[11];
    #pragma unroll
    for (int j = 0; j < 11; ++j) acc[j] = 0.f;
    for (int it = 0; it < 16; ++it) {
        int pr = pr0 + (it << 3);
        int iy = refl(ki + 2 * pr - 5);
        float4 ev = *reinterpret_cast<const float4*>(Eb + pr * 128 + ps0);
        const float4* row4 = reinterpret_cast<const float4*>(xb + iy * XPROW + 2 * ps0);
        float w[24];
        #pragma unroll
        for (int q = 0; q < 6; ++q) {
            float4 v = row4[q];
            w[4 * q] = v.x; w[4 * q + 1] = v.y; w[4 * q + 2] = v.z; w[4 * q + 3] = v.w;
        }
        #pragma unroll
        for (int j = 0; j < 11; ++j) {
            float v = acc[j];
            v = fmaf(w[j + 3], ev.x, v);
            v = fmaf(w[j + 5], ev.y, v);
            v = fmaf(w[j + 7], ev.z, v);
            v = fmaf(w[j + 9], ev.w, v);
            acc[j] = v;
        }
    }
    __shared__ float part[4][11];
    int lane = t & 63, wid = t >> 6;
    #pragma unroll
    for (int j = 0; j < 11; ++j) {
        float v = acc[j];
        #pragma unroll
        for (int off = 32; off > 0; off >>= 1)
            v += __shfl_down(v, off, 64);
        if (lane == 0) part[wid][j] = v;
    }
    __syncthreads();
    if (t < 11) {
        float s = part[0][t] + part[1][t] + part[2][t] + part[3][t];
        G[n * 968 + (ki * 11 + t) * 8 + c] = s * (1.0f / 16384.0f);
    }
}

// ---------------- Fallback kernels (R3, scalar loads, known-good) ----------
__global__ __launch_bounds__(256) void blur_kernel_ref(
        const float* __restrict__ x, const float* __restrict__ y,
        const float* __restrict__ kk, float* __restrict__ E2) {
    __shared__ float kl[121];
    int bid = blockIdx.x;
    int rowblk = bid & 15;
    int nc = bid >> 4;
    int t = threadIdx.x;
    if (t < 121) kl[t] = kk[nc * 121 + t];
    __syncthreads();
    int r = rowblk * 8 + (t >> 5);
    int ps0 = (t & 31) * 4;
    const float* xb = x + nc * 65536;
    float a0 = 0.f, a1 = 0.f, a2 = 0.f, a3 = 0.f;
    int cb = 2 * ps0 - 5;
    #pragma unroll
    for (int i = 0; i < 11; ++i) {
        int iy = refl(2 * r - 5 + i);
        const float* row = xb + iy * 256;
        float c[17];
        #pragma unroll
        for (int u = 0; u < 17; ++u) c[u] = row[refl(cb + u)];
        #pragma unroll
        for (int j = 0; j < 11; ++j) {
            float kv = kl[i * 11 + j];
            a0 = fmaf(c[j], kv, a0);
            a1 = fmaf(c[j + 2], kv, a1);
            a2 = fmaf(c[j + 4], kv, a2);
            a3 = fmaf(c[j + 6], kv, a3);
        }
    }
    int n = nc >> 3;
    int o = nc * 16384 + r * 128 + ps0;
    float4 yv = *reinterpret_cast<const float4*>(y + o);
    float e[4] = {a0 - yv.x, a1 - yv.y, a2 - yv.z, a3 - yv.w};
    int qn = o - n * 131072;
    int p = qn >> 3;
    int cbase = qn & 7;
    float* eb = E2 + n * 131072 + p;
    #pragma unroll
    for (int qq = 0; qq < 4; ++qq)
        eb[(cbase + qq) * 16384] = e[qq];
}

__global__ __launch_bounds__(256) void grad_kernel_ref(
        const float* __restrict__ x, const float* __restrict__ E2,
        float* __restrict__ G) {
    int bid = blockIdx.x;
    int ki = bid % 11;
    int nc = bid / 11;
    int n = nc >> 3, c = nc & 7;
    const float* xb = x + nc * 65536;
    const float* Eb = E2 + n * 131072 + c * 16384;
    int t = threadIdx.x;
    int ps0 = (t & 31) * 4;
    int pr0 = t >> 5;
    int cb = 2 * ps0 - 5;
    float acc[11];
    #pragma unroll
    for (int j = 0; j < 11; ++j) acc[j] = 0.f;
    for (int it = 0; it < 16; ++it) {
        int pr = pr0 + (it << 3);
        int iy = refl(ki + 2 * pr - 5);
        const float* row = xb + iy * 256;
        float cbuf[17];
        #pragma unroll
        for (int u = 0; u < 17; ++u) cbuf[u] = row[refl(cb + u)];
        float4 ev = *reinterpret_cast<const float4*>(Eb + pr * 128 + ps0);
        #pragma unroll
        for (int j = 0; j < 11; ++j) {
            float v = acc[j];
            v = fmaf(cbuf[j], ev.x, v);
            v = fmaf(cbuf[j + 2], ev.y, v);
            v = fmaf(cbuf[j + 4], ev.z, v);
            v = fmaf(cbuf[j + 6], ev.w, v);
            acc[j] = v;
        }
    }
    __shared__ float part[4][11];
    int lane = t & 63, wid = t >> 6;
    #pragma unroll
    for (int j = 0; j < 11; ++j) {
        float v = acc[j];
        #pragma unroll
        for (int off = 32; off > 0; off >>= 1)
            v += __shfl_down(v, off, 64);
        if (lane == 0) part[wid][j] = v;
    }
    __syncthreads();
    if (t < 11) {
        float s = part[0][t] + part[1][t] + part[2][t] + part[3][t];
        G[n * 968 + (ki * 11 + t) * 8 + c] = s * (1.0f / 16384.0f);
    }
}

// ---------------- K3: pronet v4 ----------------
// 704 threads = 8 ci-groups (oct) x 88 (co x yy). One ci per thread -> halved
// per-thread conv work; 11 waves for latency hiding. Weights staged with
// float4 global loads (144 per conv), scattered into 12-float padded rows.
// Partial sums exchanged via red[7][88][12] with float4 writes/reads.
struct PArgs {
    const float* W[9];
    const float* B[9];
    const float* k;
    const float* gamma;
    const float* G;
    float* out;
};

#define PLSTRIDE 20
#define WSTRIDE 12

__global__ __launch_bounds__(704) void pronet_kernel(PArgs pa) {
    __shared__ __align__(16) float P0[8 * 13 * PLSTRIDE];
    __shared__ __align__(16) float P1[8 * 13 * PLSTRIDE];
    __shared__ float G2[968];
    __shared__ float F[968];
    __shared__ __align__(16) float red[7 * 88 * WSTRIDE];
    __shared__ __align__(16) float wts[9 * 64 * WSTRIDE];
    __shared__ float bs[9 * 8];
    __shared__ float rowsum[88];
    __shared__ float inv[8];

    int n = blockIdx.x;
    int t = threadIdx.x;

    // stage weights: 144 float4 per conv, scatter to padded LDS rows.
    // wts[(widx*64 + co*8+ci)*12 + q] = W[widx][(co*8+ci)*9 + q]
    #pragma unroll
    for (int widx = 0; widx < 9; ++widx) {
        if (t < 144) {
            float4 v = reinterpret_cast<const float4*>(pa.W[widx])[t];
            float vv[4] = {v.x, v.y, v.z, v.w};
            #pragma unroll
            for (int q2 = 0; q2 < 4; ++q2) {
                int g = 4 * t + q2;
                int oc = g / 9, q = g - oc * 9;
                wts[(widx * 64 + oc) * WSTRIDE + q] = vv[q2];
            }
        } else if (t >= 640 && t < 648) {
            bs[widx * 8 + (t - 640)] = pa.B[widx][t - 640];
        }
    }
    for (int i = t; i < 8 * 13 * PLSTRIDE; i += 704) { P0[i] = 0.f; P1[i] = 0.f; }
    __syncthreads();

    float gm = pa.gamma[0] * 0.1f;
    for (int o = t; o < 968; o += 704) {
        float v = pa.k[n * 968 + o] - gm * pa.G[n * 968 + o];
        G2[o] = v;
        int co = o / 121, rem = o - co * 121;
        int yy = rem / 11, xx = rem - yy * 11;
        P0[(co * 13 + yy + 1) * PLSTRIDE + xx + 1] = v;
    }

    int oct = t / 88;                // 0..7 -> ci = oct
    int id = t - oct * 88;           // 0..87
    int co = id / 11, yy = id - co * 11;
    int ci = oct;

    // mode 0: P1 = relu(conv);  mode 1: P0 = relu(P0 + 0.1*conv);
    // mode 2: F  = relu(G2 + 0.1*conv)
    auto do_conv = [&](const float* Pin, int widx, int mode) {
        __syncthreads();
        float acc[12];
        {
            #pragma unroll
            for (int xx = 0; xx < 12; ++xx) acc[xx] = 0.f;
            const float4* wp4 = reinterpret_cast<const float4*>(
                &wts[(widx * 64 + co * 8 + ci) * WSTRIDE]);
            float4 w0 = wp4[0], w1 = wp4[1], w2 = wp4[2];
            float wv[9] = {w0.x, w0.y, w0.z, w0.w, w1.x, w1.y, w1.z, w1.w, w2.x};
            float r[3][13];
            #pragma unroll
            for (int dy = 0; dy < 3; ++dy) {
                const float* row = Pin + (ci * 13 + yy + dy) * PLSTRIDE;
                float4 a = *reinterpret_cast<const float4*>(row);
                float4 b = *reinterpret_cast<const float4*>(row + 4);
                float4 c = *reinterpret_cast<const float4*>(row + 8);
                r[dy][0] = a.x;  r[dy][1] = a.y;  r[dy][2]  = a.z;  r[dy][3]  = a.w;
                r[dy][4] = b.x;  r[dy][5] = b.y;  r[dy][6]  = b.z;  r[dy][7]  = b.w;
                r[dy][8] = c.x;  r[dy][9] = c.y;  r[dy][10] = c.z;  r[dy][11] = c.w;
                r[dy][12] = row[12];
            }
            #pragma unroll
            for (int xx = 0; xx < 11; ++xx) {
                float v = acc[xx];
                v = fmaf(r[0][xx],     wv[0], v);
                v = fmaf(r[0][xx + 1], wv[1], v);
                v = fmaf(r[0][xx + 2], wv[2], v);
                v = fmaf(r[1][xx],     wv[3], v);
                v = fmaf(r[1][xx + 1], wv[4], v);
                v = fmaf(r[1][xx + 2], wv[5], v);
                v = fmaf(r[2][xx],     wv[6], v);
                v = fmaf(r[2][xx + 1], wv[7], v);
                v = fmaf(r[2][xx + 2], wv[8], v);
                acc[xx] = v;
            }
            if (oct != 0) {
                float4* rp = reinterpret_cast<float4*>(
                    &red[((oct - 1) * 88 + id) * WSTRIDE]);
                rp[0] = make_float4(acc[0], acc[1], acc[2],  acc[3]);
                rp[1] = make_float4(acc[4], acc[5], acc[6],  acc[7]);
                rp[2] = make_float4(acc[8], acc[9], acc[10], acc[11]);
            }
        }
        __syncthreads();
        if (oct == 0) {
            float b = bs[widx * 8 + co];
            float oth[12];
            #pragma unroll
            for (int pq = 0; pq < 7; ++pq) {
                const float4* rp = reinterpret_cast<const float4*>(
                    &red[(pq * 88 + id) * WSTRIDE]);
                float4 v0 = rp[0], v1 = rp[1], v2 = rp[2];
                if (pq == 0) {
                    oth[0] = v0.x; oth[1] = v0.y; oth[2]  = v0.z; oth[3]  = v0.w;
                    oth[4] = v1.x; oth[5] = v1.y; oth[6]  = v1.z; oth[7]  = v1.w;
                    oth[8] = v2.x; oth[9] = v2.y; oth[10] = v2.z; oth[11] = v2.w;
                } else {
                    oth[0] += v0.x; oth[1] += v0.y; oth[2]  += v0.z; oth[3]  += v0.w;
                    oth[4] += v1.x; oth[5] += v1.y; oth[6]  += v1.z; oth[7]  += v1.w;
                    oth[8] += v2.x; oth[9] += v2.y; oth[10] += v2.z; oth[11] += v2.w;
                }
            }
            #pragma unroll
            for (int xx = 0; xx < 11; ++xx) {
                float v = acc[xx] + oth[xx] + b;
                int pidx = (co * 13 + yy + 1) * PLSTRIDE + xx + 1;
                if (mode == 0) {
                    P1[pidx] = fmaxf(v, 0.f);
                } else if (mode == 1) {
                    float p = P0[pidx];
                    P0[pidx] = fmaxf(fmaf(0.1f, v, p), 0.f);
                } else {
                    int fo = co * 121 + yy * 11 + xx;
                    F[fo] = fmaxf(fmaf(0.1f, v, G2[fo]), 0.f);
                }
            }
        }
    };

    #pragma unroll
    for (int rb = 0; rb < 4; ++rb) {
        do_conv(P0, 2 * rb, 0);
        do_conv(P1, 2 * rb + 1, 1);
    }
    do_conv(P0, 8, 2);
    __syncthreads();

    if (t < 88) {
        int tco = t / 11, tyy = t - tco * 11;
        float s = 0.f;
        #pragma unroll
        for (int xx = 0; xx < 11; ++xx) s += F[tco * 121 + tyy * 11 + xx];
        rowsum[t] = s;
    }
    __syncthreads();
    if (t < 8) {
        float s = 0.f;
        #pragma unroll
        for (int j = 0; j < 11; ++j) s += rowsum[t * 11 + j];
        inv[t] = 1.f / s;
    }
    __syncthreads();
    for (int o = t; o < 968; o += 704)
        pa.out[n * 968 + o] = F[o] * inv[o / 121];
}

extern "C" void kernel_launch(void* const* d_in, const int* in_sizes, int n_in,
                              void* d_out, int out_size, void* d_ws, size_t ws_size,
                              hipStream_t stream) {
    const float* x = (const float*)d_in[0];
    const float* y = (const float*)d_in[1];
    const float* k = (const float*)d_in[2];
    const float* gamma = (const float*)d_in[4];

    const size_t xpad_fl = (size_t)64 * 256 * XPROW;
    const size_t e2_fl = (size_t)8 * 131072;
    const size_t need = (xpad_fl + e2_fl + 7744) * sizeof(float);

    float* G;
    if (ws_size >= need) {
        float* xpad = (float*)d_ws;
        float* E2 = xpad + xpad_fl;
        G = E2 + e2_fl;
        pad_kernel<<<256, 256, 0, stream>>>(x, xpad);
        blur_kernel<<<1024, 256, 0, stream>>>(xpad, y, k, E2);
        grad_kernel<<<704, 256, 0, stream>>>(xpad, E2, G);
    } else {
        float* E2 = (float*)d_ws;
        G = E2 + e2_fl;
        blur_kernel_ref<<<1024, 256, 0, stream>>>(x, y, k, E2);
        grad_kernel_ref<<<704, 256, 0, stream>>>(x, E2, G);
    }

    PArgs pa;
    for (int i = 0; i < 9; ++i) {
        pa.W[i] = (const float*)d_in[5 + 2 * i];
        pa.B[i] = (const float*)d_in[6 + 2 * i];
    }
    pa.k = k;
    pa.gamma = gamma;
    pa.G = G;
    pa.out = (float*)d_out;
    pronet_kernel<<<8, 704, 0, stream>>>(pa);
}